// Round 4
// baseline (109.715 us; speedup 1.0000x reference)
//
#include <hip/hip_runtime.h>

// Bilinear warp via flow field.
// im:   [B=8, H=256, W=256, C=64] float32
// flow: [B, H, W, 2]              float32
// out:  [B, H, W, C]              float32
//
// Mapping: 4 lanes per output texel, each lane handles 16 channels
// (4x float4). Channels innermost-contiguous -> each corner read is
// 4 lanes x 64B = 256B fully coalesced, and each thread keeps 16 gather
// loads in flight (deep MLP). Output stores are nontemporal (write-once
// stream) so the 134MB write stream doesn't pollute L2.

constexpr int Bc = 8, Hc = 256, Wc = 256, Cc = 64;

// clang native vector type (HIP's float4 is a class -> rejected by
// __builtin_nontemporal_store)
typedef float v4f __attribute__((ext_vector_type(4)));
typedef float v2f __attribute__((ext_vector_type(2)));

__global__ __launch_bounds__(256) void SWN_warp_kernel(
    const float* __restrict__ im,
    const float* __restrict__ flow,
    float* __restrict__ out)
{
    const int tid = blockIdx.x * 256 + threadIdx.x;
    const int p   = tid >> 2;        // texel index in [0, B*H*W)
    const int c16 = tid & 3;         // which 64B chunk of the 64 channels

    const int w = p & (Wc - 1);
    const int h = (p >> 8) & (Hc - 1);
    const int b = p >> 16;

    // flow for this texel (4 lanes read the same 8B -> broadcast)
    const v2f fl = *reinterpret_cast<const v2f*>(flow + (size_t)p * 2);

    const float Hf = (float)Hc;
    const float Wf = (float)Wc;

    // normalized meshgrid, matching jnp.linspace(-1, 1, N)
    float gx = -1.0f + 2.0f * (float)w / (float)(Wc - 1);
    float gy = -1.0f + 2.0f * (float)h / (float)(Hc - 1);

    // reference op order
    float x = gx + fl.x / Hf;
    float y = gy + fl.y / Hf;
    x = (x + 1.0f) * Wf * 0.5f;
    y = (y + 1.0f) * Hf * 0.5f;

    const float fx0 = floorf(x);
    const float fy0 = floorf(y);
    int x0 = (int)fx0;
    int y0 = (int)fy0;
    int x1 = x0 + 1;
    int y1 = y0 + 1;

    const int mx = Hc - 1;  // reference clips both axes to H-1
    int x0c = min(max(x0, 0), mx);
    int x1c = min(max(x1, 0), mx);
    int y0c = min(max(y0, 0), mx);
    int y1c = min(max(y1, 0), mx);

    const float x0f = (float)x0c;
    const float x1f = (float)x1c;
    const float y0f = (float)y0c;
    const float y1f = (float)y1c;

    const float wa = (x1f - x) * (y1f - y);
    const float wb = (x1f - x) * (y - y0f);
    const float wcw = (x - x0f) * (y1f - y);
    const float wd = (x - x0f) * (y - y0f);

    const v4f* imb = reinterpret_cast<const v4f*>(
        im + (size_t)b * Hc * Wc * Cc);
    const int CV = Cc / 4;  // 16 float4s per texel

    // uint32 float4-indices within batch (max ~1M, fits easily)
    const unsigned ia = (unsigned)(y0c * Wc + x0c) * CV + c16 * 4;
    const unsigned ib = (unsigned)(y1c * Wc + x0c) * CV + c16 * 4;
    const unsigned ic = (unsigned)(y0c * Wc + x1c) * CV + c16 * 4;
    const unsigned id = (unsigned)(y1c * Wc + x1c) * CV + c16 * 4;

    // 16 independent loads issued back-to-back (deep MLP)
    const v4f Ia0 = imb[ia],     Ia1 = imb[ia + 1];
    const v4f Ia2 = imb[ia + 2], Ia3 = imb[ia + 3];
    const v4f Ib0 = imb[ib],     Ib1 = imb[ib + 1];
    const v4f Ib2 = imb[ib + 2], Ib3 = imb[ib + 3];
    const v4f Ic0 = imb[ic],     Ic1 = imb[ic + 1];
    const v4f Ic2 = imb[ic + 2], Ic3 = imb[ic + 3];
    const v4f Id0 = imb[id],     Id1 = imb[id + 1];
    const v4f Id2 = imb[id + 2], Id3 = imb[id + 3];

    v4f o0 = wa * Ia0 + wb * Ib0 + wcw * Ic0 + wd * Id0;
    v4f o1 = wa * Ia1 + wb * Ib1 + wcw * Ic1 + wd * Id1;
    v4f o2 = wa * Ia2 + wb * Ib2 + wcw * Ic2 + wd * Id2;
    v4f o3 = wa * Ia3 + wb * Ib3 + wcw * Ic3 + wd * Id3;

    v4f* outp = reinterpret_cast<v4f*>(out) + (size_t)p * CV + c16 * 4;
    __builtin_nontemporal_store(o0, outp);
    __builtin_nontemporal_store(o1, outp + 1);
    __builtin_nontemporal_store(o2, outp + 2);
    __builtin_nontemporal_store(o3, outp + 3);
}

extern "C" void kernel_launch(void* const* d_in, const int* in_sizes, int n_in,
                              void* d_out, int out_size, void* d_ws, size_t ws_size,
                              hipStream_t stream) {
    const float* im   = (const float*)d_in[0];
    const float* flow = (const float*)d_in[1];
    float* out        = (float*)d_out;

    // B*H*W texels * 4 threads each / 256 threads per block
    const int total_threads = Bc * Hc * Wc * 4;
    const int blocks = total_threads / 256;
    SWN_warp_kernel<<<blocks, 256, 0, stream>>>(im, flow, out);
}

// Round 5
// 43.898 us; speedup vs baseline: 2.4993x; 2.4993x over previous
//
#include <hip/hip_runtime.h>

// Bilinear warp via flow field.
// im:   [B=8, H=256, W=256, C=64] float32
// flow: [B, H, W, 2]              float32
// out:  [B, H, W, C]              float32
//
// Mapping: 8 lanes per output texel; lane c owns float4 chunks {c, c+8}
// (INTERLEAVED, not consecutive) so that every load/store instruction has
// the 8 lanes covering a dense 128B run. (Round-4 lesson: consecutive
// chunks per lane -> 64B-stride 16B stores -> 1.68x HBM write
// amplification.) Output stores are nontemporal (write-once stream).

constexpr int Bc = 8, Hc = 256, Wc = 256, Cc = 64;

// clang native vector type (HIP's float4 is a class -> rejected by
// __builtin_nontemporal_store)
typedef float v4f __attribute__((ext_vector_type(4)));
typedef float v2f __attribute__((ext_vector_type(2)));

__global__ __launch_bounds__(256) void SWN_warp_kernel(
    const float* __restrict__ im,
    const float* __restrict__ flow,
    float* __restrict__ out)
{
    const int tid = blockIdx.x * 256 + threadIdx.x;
    const int p   = tid >> 3;        // texel index in [0, B*H*W)
    const int c8i = tid & 7;         // lane within texel group

    const int w = p & (Wc - 1);
    const int h = (p >> 8) & (Hc - 1);
    const int b = p >> 16;

    // flow for this texel (8 lanes read the same 8B -> broadcast)
    const v2f fl = *reinterpret_cast<const v2f*>(flow + (size_t)p * 2);

    const float Hf = (float)Hc;
    const float Wf = (float)Wc;

    // normalized meshgrid, matching jnp.linspace(-1, 1, N)
    float gx = -1.0f + 2.0f * (float)w / (float)(Wc - 1);
    float gy = -1.0f + 2.0f * (float)h / (float)(Hc - 1);

    // reference op order
    float x = gx + fl.x / Hf;
    float y = gy + fl.y / Hf;
    x = (x + 1.0f) * Wf * 0.5f;
    y = (y + 1.0f) * Hf * 0.5f;

    const float fx0 = floorf(x);
    const float fy0 = floorf(y);
    int x0 = (int)fx0;
    int y0 = (int)fy0;
    int x1 = x0 + 1;
    int y1 = y0 + 1;

    const int mx = Hc - 1;  // reference clips both axes to H-1
    int x0c = min(max(x0, 0), mx);
    int x1c = min(max(x1, 0), mx);
    int y0c = min(max(y0, 0), mx);
    int y1c = min(max(y1, 0), mx);

    const float x0f = (float)x0c;
    const float x1f = (float)x1c;
    const float y0f = (float)y0c;
    const float y1f = (float)y1c;

    const float wa = (x1f - x) * (y1f - y);
    const float wb = (x1f - x) * (y - y0f);
    const float wcw = (x - x0f) * (y1f - y);
    const float wd = (x - x0f) * (y - y0f);

    const v4f* imb = reinterpret_cast<const v4f*>(
        im + (size_t)b * Hc * Wc * Cc);
    const int CV = Cc / 4;  // 16 float4s per texel

    // uint32 float4-indices within batch; lane owns chunks c8i and c8i+8
    const unsigned ia = (unsigned)(y0c * Wc + x0c) * CV + c8i;
    const unsigned ib = (unsigned)(y1c * Wc + x0c) * CV + c8i;
    const unsigned ic = (unsigned)(y0c * Wc + x1c) * CV + c8i;
    const unsigned id = (unsigned)(y1c * Wc + x1c) * CV + c8i;

    // 8 independent loads in flight; each instruction is 8 lanes x 16B
    // = 128B dense.
    const v4f Ia0 = imb[ia],     Ia1 = imb[ia + 8];
    const v4f Ib0 = imb[ib],     Ib1 = imb[ib + 8];
    const v4f Ic0 = imb[ic],     Ic1 = imb[ic + 8];
    const v4f Id0 = imb[id],     Id1 = imb[id + 8];

    v4f o0 = wa * Ia0 + wb * Ib0 + wcw * Ic0 + wd * Id0;
    v4f o1 = wa * Ia1 + wb * Ib1 + wcw * Ic1 + wd * Id1;

    v4f* outp = reinterpret_cast<v4f*>(out) + (size_t)p * CV + c8i;
    __builtin_nontemporal_store(o0, outp);
    __builtin_nontemporal_store(o1, outp + 8);
}

extern "C" void kernel_launch(void* const* d_in, const int* in_sizes, int n_in,
                              void* d_out, int out_size, void* d_ws, size_t ws_size,
                              hipStream_t stream) {
    const float* im   = (const float*)d_in[0];
    const float* flow = (const float*)d_in[1];
    float* out        = (float*)d_out;

    // B*H*W texels * 8 threads each / 256 threads per block
    const int total_threads = Bc * Hc * Wc * 8;
    const int blocks = total_threads / 256;
    SWN_warp_kernel<<<blocks, 256, 0, stream>>>(im, flow, out);
}